// Round 1
// baseline (90607.452 us; speedup 1.0000x reference)
//
#include <hip/hip_runtime.h>
#include <hip/hip_cooperative_groups.h>

namespace cg = cooperative_groups;

#define TLEN 2048
#define NB   64
#define NH   256
#define NF   64
#define NCIN 16
#define NOUT 20
#define HB   (NH * NB)   // 16384 floats per h buffer

__device__ __forceinline__ float sigf(float x) { return 1.0f / (1.0f + __expf(-x)); }
__device__ __forceinline__ float tanh_f(float x) {
    x = fminf(fmaxf(x, -15.0f), 15.0f);
    float e = __expf(2.0f * x);
    return (e - 1.0f) / (e + 1.0f);
}

// ---------------- Pass A: conv + relu, per-(f, t-quarter) partial sums for BN stats
__global__ __launch_bounds__(256) void conv_stats_kernel(
    const float* __restrict__ x, const float* __restrict__ cw, const float* __restrict__ cb,
    float* __restrict__ partials)
{
    const int blk = blockIdx.x;          // 256 blocks
    const int f = blk >> 2, tq = blk & 3;
    const int tid = threadIdx.x;

    float w[NCIN][3];
#pragma unroll
    for (int c = 0; c < NCIN; ++c) {
        w[c][0] = cw[(f * NCIN + c) * 3 + 0];
        w[c][1] = cw[(f * NCIN + c) * 3 + 1];
        w[c][2] = cw[(f * NCIN + c) * 3 + 2];
    }
    const float bias = cb[f];
    float s = 0.f, s2 = 0.f;

    for (int i = 0; i < 128; ++i) {
        int idx = tq * 32768 + i * 256 + tid;   // (B*T)/4 elements per block
        int b = idx >> 11;
        int t = idx & 2047;
        const float* xb = x + (size_t)b * NCIN * TLEN;
        float acc = bias;
#pragma unroll
        for (int c = 0; c < NCIN; ++c) {
            const float* xc = xb + (size_t)c * TLEN + t;
            float xm = (t > 0)        ? xc[-1] : 0.f;
            float x0 = xc[0];
            float xp = (t < TLEN - 1) ? xc[1]  : 0.f;
            acc = fmaf(xm, w[c][0], acc);
            acc = fmaf(x0, w[c][1], acc);
            acc = fmaf(xp, w[c][2], acc);
        }
        float y = fmaxf(acc, 0.f);
        s += y; s2 = fmaf(y, y, s2);
    }

    __shared__ float rs[256], rs2[256];
    rs[tid] = s; rs2[tid] = s2;
    __syncthreads();
    for (int off = 128; off > 0; off >>= 1) {
        if (tid < off) { rs[tid] += rs[tid + off]; rs2[tid] += rs2[tid + off]; }
        __syncthreads();
    }
    if (tid == 0) {
        partials[(f * 4 + tq) * 2 + 0] = rs[0];
        partials[(f * 4 + tq) * 2 + 1] = rs2[0];
    }
}

// ---------------- Pass B: conv + relu + BN affine, write feats[t][f][b]
__global__ __launch_bounds__(256) void conv_bn_feats_kernel(
    const float* __restrict__ x, const float* __restrict__ cw, const float* __restrict__ cb,
    const float* __restrict__ gamma, const float* __restrict__ beta,
    const float* __restrict__ partials, float* __restrict__ feats)
{
    const int t = blockIdx.x;            // 2048 blocks
    const int tid = threadIdx.x;
    const int b = tid & 63, fq = tid >> 6;

    __shared__ float sc[NF], sh[NF];
    if (tid < NF) {
        int f = tid;
        float s = 0.f, s2 = 0.f;
        for (int q = 0; q < 4; ++q) {
            s  += partials[(f * 4 + q) * 2 + 0];
            s2 += partials[(f * 4 + q) * 2 + 1];
        }
        const float inv_n = 1.0f / ((float)NB * (float)TLEN);
        float mean = s * inv_n;
        float var  = s2 * inv_n - mean * mean;
        float iv   = rsqrtf(var + 1e-5f);
        float scale = gamma[f] * iv;
        sc[f] = scale;
        sh[f] = beta[f] - mean * scale;
    }
    __syncthreads();

    float xr[NCIN][3];
    const float* xb = x + (size_t)b * NCIN * TLEN;
#pragma unroll
    for (int c = 0; c < NCIN; ++c) {
        const float* xc = xb + (size_t)c * TLEN + t;
        xr[c][0] = (t > 0)        ? xc[-1] : 0.f;
        xr[c][1] = xc[0];
        xr[c][2] = (t < TLEN - 1) ? xc[1]  : 0.f;
    }

    float* ft = feats + (size_t)t * (NF * NB);
    for (int fi = 0; fi < 16; ++fi) {
        int f = fq * 16 + fi;
        float acc = cb[f];
#pragma unroll
        for (int c = 0; c < NCIN; ++c) {
            acc = fmaf(xr[c][0], cw[(f * NCIN + c) * 3 + 0], acc);
            acc = fmaf(xr[c][1], cw[(f * NCIN + c) * 3 + 1], acc);
            acc = fmaf(xr[c][2], cw[(f * NCIN + c) * 3 + 2], acc);
        }
        float y = fmaxf(acc, 0.f);
        ft[f * NB + b] = fmaf(y, sc[f], sh[f]);
    }
}

#define QUAD() do { \
    a0 = fmaf(x0, w0.x, a0); a0 = fmaf(x1, w0.y, a0); a0 = fmaf(x2, w0.z, a0); a0 = fmaf(x3, w0.w, a0); \
    a1 = fmaf(x0, w1.x, a1); a1 = fmaf(x1, w1.y, a1); a1 = fmaf(x2, w1.z, a1); a1 = fmaf(x3, w1.w, a1); \
    a2 = fmaf(x0, w2.x, a2); a2 = fmaf(x1, w2.y, a2); a2 = fmaf(x2, w2.z, a2); a2 = fmaf(x3, w2.w, a2); \
    a3 = fmaf(x0, w3.x, a3); a3 = fmaf(x1, w3.y, a3); a3 = fmaf(x2, w3.z, a3); a3 = fmaf(x3, w3.w, a3); \
} while (0)

// ---------------- Cooperative LSTM + FC kernel
// Grid: 256 blocks x 256 threads.
//   blocks [0,128):   layer-0, hidden units j0=blk*2, j0+1   (K = 64 feats + 256 h0 = 320)
//   blocks [128,256): layer-1, hidden units j0=(blk-128)*2   (K = 256 h0 + 256 h1 = 512)
//   blocks [0,20):    additionally compute FC output row o=blk
// Phase p: L0 computes step t=p, L1 computes step t=p-1, FC emits t=p-2. One grid.sync per phase.
__global__ __launch_bounds__(256) void lstm_kernel(
    const float* __restrict__ feats,
    const float* __restrict__ wih0, const float* __restrict__ whh0,
    const float* __restrict__ bih0, const float* __restrict__ bhh0,
    const float* __restrict__ wih1, const float* __restrict__ whh1,
    const float* __restrict__ bih1, const float* __restrict__ bhh1,
    const float* __restrict__ fcw,  const float* __restrict__ fcb,
    float* __restrict__ h0, float* __restrict__ h1,
    float* __restrict__ c0, float* __restrict__ c1,
    float* __restrict__ out)
{
    cg::grid_group grid = cg::this_grid();
    const int blk = blockIdx.x;
    const int tid = threadIdx.x;
    const int b  = tid & 63;
    const int q  = tid >> 6;   // wave id 0..3
    const int u  = q & 1;      // which of the block's 2 hidden units
    const int kh = q >> 1;     // which K-half
    const bool isL1 = (blk >= 128);
    const int j0 = (isL1 ? blk - 128 : blk) * 2;

    __shared__ float  W[8 * 512];      // rows: [u*4+gate][k], stride 512
    __shared__ float  bias8[8];
    __shared__ float4 red4[2][64];
    __shared__ float  red1[4][64];

    // ---- load weights into LDS (once)
    for (int r = 0; r < 8; ++r) {
        int uu = r >> 2, g = r & 3;
        int grow = g * 256 + j0 + uu;   // PyTorch gate order i,f,g,o
        if (!isL1) {
            for (int k = tid; k < 320; k += 256)
                W[r * 512 + k] = (k < 64) ? wih0[grow * 64 + k] : whh0[grow * 256 + (k - 64)];
        } else {
            for (int k = tid; k < 512; k += 256)
                W[r * 512 + k] = (k < 256) ? wih1[grow * 256 + k] : whh1[grow * 256 + (k - 256)];
        }
    }
    if (tid < 8) {
        int r = tid, uu = r >> 2, g = r & 3;
        int grow = g * 256 + j0 + uu;
        bias8[r] = isL1 ? (bih1[grow] + bhh1[grow]) : (bih0[grow] + bhh0[grow]);
    }
    // ---- zero initial state (parity-1 h buffers, c)
    if (tid < 128) {
        int uu = tid >> 6, bb = tid & 63;
        int j = j0 + uu;
        if (!isL1) { h0[HB + j * 64 + bb] = 0.f; c0[j * 64 + bb] = 0.f; }
        else       { h1[HB + j * 64 + bb] = 0.f; c1[j * 64 + bb] = 0.f; }
    }
    __syncthreads();
    grid.sync();

    const float4* W0v = (const float4*)(W + (u * 4 + 0) * 512);
    const float4* W1v = (const float4*)(W + (u * 4 + 1) * 512);
    const float4* W2v = (const float4*)(W + (u * 4 + 2) * 512);
    const float4* W3v = (const float4*)(W + (u * 4 + 3) * 512);

    for (int p = 0; p < TLEN + 2; ++p) {
        if (!isL1) {
            if (p < TLEN) {
                const float* h0prev = h0 + ((p + 1) & 1) * HB;   // step p-1
                float a0, a1, a2, a3;
                if (kh == 0) {
                    a0 = bias8[u * 4 + 0]; a1 = bias8[u * 4 + 1];
                    a2 = bias8[u * 4 + 2]; a3 = bias8[u * 4 + 3];
                    const float* fp = feats + (size_t)p * (NF * NB) + b;
#pragma unroll 4
                    for (int k4 = 0; k4 < 16; ++k4) {            // k 0..63 : conv feats
                        float4 w0 = W0v[k4], w1 = W1v[k4], w2 = W2v[k4], w3 = W3v[k4];
                        float x0 = fp[(4 * k4 + 0) * 64], x1 = fp[(4 * k4 + 1) * 64];
                        float x2 = fp[(4 * k4 + 2) * 64], x3 = fp[(4 * k4 + 3) * 64];
                        QUAD();
                    }
                    const float* hp = h0prev + b;
#pragma unroll 4
                    for (int k4 = 16; k4 < 40; ++k4) {           // k 64..159 : h0 rows 0..95
                        float4 w0 = W0v[k4], w1 = W1v[k4], w2 = W2v[k4], w3 = W3v[k4];
                        int hk = 4 * k4 - 64;
                        float x0 = hp[(hk + 0) * 64], x1 = hp[(hk + 1) * 64];
                        float x2 = hp[(hk + 2) * 64], x3 = hp[(hk + 3) * 64];
                        QUAD();
                    }
                } else {
                    a0 = a1 = a2 = a3 = 0.f;
                    const float* hp = h0prev + b;
#pragma unroll 4
                    for (int k4 = 40; k4 < 80; ++k4) {           // k 160..319 : h0 rows 96..255
                        float4 w0 = W0v[k4], w1 = W1v[k4], w2 = W2v[k4], w3 = W3v[k4];
                        int hk = 4 * k4 - 64;
                        float x0 = hp[(hk + 0) * 64], x1 = hp[(hk + 1) * 64];
                        float x2 = hp[(hk + 2) * 64], x3 = hp[(hk + 3) * 64];
                        QUAD();
                    }
                    red4[u][b] = make_float4(a0, a1, a2, a3);
                }
                __syncthreads();
                if (kh == 0) {
                    float4 r = red4[u][b];
                    float gi = a0 + r.x, gf = a1 + r.y, gg = a2 + r.z, go = a3 + r.w;
                    int j = j0 + u;
                    float c = c0[j * 64 + b];
                    float i_ = sigf(gi), f_ = sigf(gf), g_ = tanh_f(gg), o_ = sigf(go);
                    c = fmaf(f_, c, i_ * g_);
                    float h = o_ * tanh_f(c);
                    c0[j * 64 + b] = c;
                    h0[(p & 1) * HB + j * 64 + b] = h;
                }
            }
            if (blk < NOUT && p >= 2) {                          // FC row o=blk, t=p-2
                int t = p - 2;
                const float* h1t = h1 + (p & 1) * HB;            // step p-2 parity
                const float* fw = fcw + blk * NH + q * 64;
                const float* hp = h1t + q * 64 * NB + b;
                float acc = 0.f;
#pragma unroll 4
                for (int k = 0; k < 64; ++k) acc = fmaf(hp[k * 64], fw[k], acc);
                red1[q][b] = acc;
                __syncthreads();
                if (q == 0) {
                    float sres = red1[0][b] + red1[1][b] + red1[2][b] + red1[3][b] + fcb[blk];
                    out[((size_t)b * NOUT + blk) * TLEN + t] = sres;
                }
            }
        } else {
            if (p >= 1 && p <= TLEN) {
                const float* h0cur  = h0 + ((p + 1) & 1) * HB;   // step p-1
                const float* h1prev = h1 + (p & 1) * HB;         // step p-2
                const float* Xs = ((kh == 0) ? h0cur : h1prev) + b;
                const int kbase = kh * 64;                       // W quad base
                float a0, a1, a2, a3;
                if (kh == 0) {
                    a0 = bias8[u * 4 + 0]; a1 = bias8[u * 4 + 1];
                    a2 = bias8[u * 4 + 2]; a3 = bias8[u * 4 + 3];
                } else { a0 = a1 = a2 = a3 = 0.f; }
#pragma unroll 4
                for (int k4 = 0; k4 < 64; ++k4) {
                    float4 w0 = W0v[kbase + k4], w1 = W1v[kbase + k4];
                    float4 w2 = W2v[kbase + k4], w3 = W3v[kbase + k4];
                    float x0 = Xs[(4 * k4 + 0) * 64], x1 = Xs[(4 * k4 + 1) * 64];
                    float x2 = Xs[(4 * k4 + 2) * 64], x3 = Xs[(4 * k4 + 3) * 64];
                    QUAD();
                }
                if (kh == 1) red4[u][b] = make_float4(a0, a1, a2, a3);
                __syncthreads();
                if (kh == 0) {
                    float4 r = red4[u][b];
                    float gi = a0 + r.x, gf = a1 + r.y, gg = a2 + r.z, go = a3 + r.w;
                    int j = j0 + u;
                    float c = c1[j * 64 + b];
                    float i_ = sigf(gi), f_ = sigf(gf), g_ = tanh_f(gg), o_ = sigf(go);
                    c = fmaf(f_, c, i_ * g_);
                    float h = o_ * tanh_f(c);
                    c1[j * 64 + b] = c;
                    h1[((p + 1) & 1) * HB + j * 64 + b] = h;     // step p-1 parity
                }
            }
        }
        grid.sync();
    }
}

extern "C" void kernel_launch(void* const* d_in, const int* in_sizes, int n_in,
                              void* d_out, int out_size, void* d_ws, size_t ws_size,
                              hipStream_t stream) {
    (void)in_sizes; (void)n_in; (void)out_size; (void)ws_size;
    const float* x      = (const float*)d_in[0];
    const float* conv_w = (const float*)d_in[1];
    const float* conv_b = (const float*)d_in[2];
    const float* gamma  = (const float*)d_in[3];
    const float* beta   = (const float*)d_in[4];
    const float* wih0   = (const float*)d_in[5];
    const float* whh0   = (const float*)d_in[6];
    const float* bih0   = (const float*)d_in[7];
    const float* bhh0   = (const float*)d_in[8];
    const float* wih1   = (const float*)d_in[9];
    const float* whh1   = (const float*)d_in[10];
    const float* bih1   = (const float*)d_in[11];
    const float* bhh1   = (const float*)d_in[12];
    const float* fcw    = (const float*)d_in[13];
    const float* fcb    = (const float*)d_in[14];
    float* out = (float*)d_out;

    char* ws = (char*)d_ws;
    float* feats    = (float*)(ws);                              // 2048*64*64*4 = 33,554,432 B
    float* partials = (float*)(ws + 33554432);                   // 512 floats
    float* h0       = (float*)(ws + 33556480);                   // 2*16384 floats
    float* h1       = (float*)(ws + 33556480 + 131072);
    float* c0       = (float*)(ws + 33556480 + 262144);
    float* c1       = (float*)(ws + 33556480 + 327680);

    hipLaunchKernelGGL(conv_stats_kernel, dim3(256), dim3(256), 0, stream,
                       x, conv_w, conv_b, partials);
    hipLaunchKernelGGL(conv_bn_feats_kernel, dim3(2048), dim3(256), 0, stream,
                       x, conv_w, conv_b, gamma, beta, partials, feats);

    void* args[] = { (void*)&feats,
                     (void*)&wih0, (void*)&whh0, (void*)&bih0, (void*)&bhh0,
                     (void*)&wih1, (void*)&whh1, (void*)&bih1, (void*)&bhh1,
                     (void*)&fcw,  (void*)&fcb,
                     (void*)&h0, (void*)&h1, (void*)&c0, (void*)&c1,
                     (void*)&out };
    hipLaunchCooperativeKernel((void*)lstm_kernel, dim3(256), dim3(256), args, 0, stream);
}